// Round 8
// baseline (194.048 us; speedup 1.0000x reference)
//
#include <hip/hip_runtime.h>
#include <hip/hip_bf16.h>

// OneStep: out = W - c * K^T (K W - V),  c = 0.2/(CTX*D) = 9.5367431640625e-8
// W:(4096,4096) K:(512,4096) V:(512,4096) fp32 -> out (4096,4096) fp32.
// bf16 MFMA w/ fp32 acc => absmax 2.441e-4 = 1 bf16 ulp (threshold 1.69e-3).
//
// R13 post-mortem: top-5 now all harness fillBuffer poisons (~80us fixed tax
// in dur_us). Controllable: t_all ~22 (HBM floor), k1 ~39, k2 ~40.
// Streaming law v2 (6 pts incl. m97 recompute): gld16/L2 K-loops cap at
// ~21 B/cyc/CU once >=2 blocks/CU; only TRAFFIC is left as a lever.
// R14: k1 -> K-split S=4, 128x128 tile (traffic 537->268 MB), grid
// (32, 4cb x 4ks) = 512 blocks = 2/CU; partial f32 sums to Rp (32 MB, ws);
// tiny k1_reduce does Rt = sum(Rp) - Vt (L3-warm, ~6us). Staging = R12's
// proven slot-XOR units (16 A + 16 B of 8rows x 128B), 2-phase dbuf,
// acc[4][4]/wave, direct dword epilogue. k2/t_all untouched.

typedef __bf16 bf16_t;
typedef __bf16 bf16x8 __attribute__((ext_vector_type(8)));
typedef float f32x4 __attribute__((ext_vector_type(4)));

#define D_DIM 4096
#define CTX_N 512
#define UPD_SCALE 9.5367431640625e-8f

__device__ __forceinline__ void gld16(const bf16_t* g, bf16_t* l) {
    __builtin_amdgcn_global_load_lds(
        (const __attribute__((address_space(1))) void*)g,
        (__attribute__((address_space(3))) void*)l, 16, 0, 0);
}

// ---- transpose+convert: src (M x N) fp32 tile -> dstT (N x M) bf16
//      [+ dstN (M x N) bf16].  64x64 tile at (bx,by); pad-65 (2-way = free).
__device__ __forceinline__ void t_body2(
    float* tile, const float* __restrict__ src, bf16_t* __restrict__ dstT,
    bf16_t* __restrict__ dstN, int M, int N, int bx, int by)
{
    const int tid = threadIdx.x;
    const int C0 = bx * 64, R0 = by * 64;
    const int r  = tid >> 2, cs = (tid & 3) * 16;

    const float* s = src + (size_t)(R0 + r) * N + C0 + cs;
    float f[16];
#pragma unroll
    for (int u = 0; u < 4; ++u) {
        const float4 v = ((const float4*)s)[u];
        f[4 * u + 0] = v.x; f[4 * u + 1] = v.y; f[4 * u + 2] = v.z; f[4 * u + 3] = v.w;
    }
#pragma unroll
    for (int u = 0; u < 16; ++u) tile[r * 65 + cs + u] = f[u];

    if (dstN) {
        bf16x8 v0, v1;
#pragma unroll
        for (int u = 0; u < 8; ++u) { v0[u] = (bf16_t)f[u]; v1[u] = (bf16_t)f[8 + u]; }
        bf16_t* d = dstN + (size_t)(R0 + r) * N + C0 + cs;
        *(bf16x8*)d = v0; *(bf16x8*)(d + 8) = v1;
    }
    __syncthreads();

    bf16x8 o0, o1;
#pragma unroll
    for (int u = 0; u < 8; ++u) {
        o0[u] = (bf16_t)tile[(cs + u) * 65 + r];
        o1[u] = (bf16_t)tile[(cs + 8 + u) * 65 + r];
    }
    bf16_t* d = dstT + (size_t)(C0 + r) * M + R0 + cs;
    *(bf16x8*)d = o0; *(bf16x8*)(d + 8) = o1;
}

// One launch for all three transposes: y<64 -> W, 64..71 -> K(+Kb), 72..79 -> V
__global__ __launch_bounds__(256) void t_all(
    const float* __restrict__ W, const float* __restrict__ K,
    const float* __restrict__ V, bf16_t* __restrict__ Wt,
    bf16_t* __restrict__ Kt, bf16_t* __restrict__ Kb, bf16_t* __restrict__ Vt)
{
    __shared__ float tile[64 * 65];
    const int y = blockIdx.y;
    if (y < 64)      t_body2(tile, W, Wt, nullptr, D_DIM, D_DIM, blockIdx.x, y);
    else if (y < 72) t_body2(tile, K, Kt, Kb,      CTX_N, D_DIM, blockIdx.x, y - 64);
    else             t_body2(tile, V, Vt, nullptr, CTX_N, D_DIM, blockIdx.x, y - 72);
}

// MFMA 16x16x32 bf16 (m89/m91): A/B frag: row=lane&15, k=quad*8+j (8 bf16);
// C/D: col=lane&15, row=quad*4+reg.  D[m][n] = sum_k A(m,k)*B(n,k).

// ---- K1a: Rp[ks][j][c] = sum_{k in split ks} Wt[j][k]*Kb[c][k]  (f32) ----
// 128(j) x 128(c) x Ksplit4 (K=1024 each), grid (32, 16: y = cb + 4*ks) =
// 512 blocks = 2/CU (streaming law ok). 256 threads, 4 waves as 2m x 2n,
// each 64x64 out (acc[4][4]). BK=64: A = 16 units, B = 16 units; unit =
// 8 rows x 128B (1 KB), slot-XOR staged (R12 pattern): gld16 lane l sources
// global (row l>>3, seg (l&7)^(l>>3)), LDS dest lane-linear; frag read
// slot = r3*8 + ((kk*4+quad)^r3) -> conflict-free b128. Wave w stages A
// units w*4..w*4+3 and B units w*4..w*4+3 (8 gld16/thread/step).
// 2-phase dbuf (2 x 32 KB), stage(t+1) before compute(t), 1 barrier/step.
// Default id%8 = bx%8: the 16 y-blocks sharing a Wt j-slice -> one XCD.

__global__ __launch_bounds__(256, 2) void k1_partial(
    const bf16_t* __restrict__ Wt, const bf16_t* __restrict__ Kb,
    float* __restrict__ Rp)
{
    __shared__ __align__(16) bf16_t stg[2 * 16384];  // 2 x (A 16KB + B 16KB)

    const int tid = threadIdx.x, wave = tid >> 6, lane = tid & 63;
    const int j0 = blockIdx.x * 128;
    const int cb = blockIdx.y & 3, ks = blockIdx.y >> 2;
    const int c0 = cb * 128;
    const size_t k0 = (size_t)ks * 1024;
    const int l15 = lane & 15, quad = lane >> 4;
    const int wm = wave >> 1, wn = wave & 1;   // wave's 64x64 output pos

    f32x4 acc[4][4] = {};

    // Staging source (slot-XOR pre-permuted): lane l -> row l>>3,
    // seg ((l&7)^(l>>3)) within the unit's 128B row window.
    const int rl = lane >> 3;                  // row within unit 0..7
    const int sl = ((lane & 7) ^ rl) * 8;      // permuted 16B seg (elems)

    const bf16_t* gA[4];
    const bf16_t* gB[4];
#pragma unroll
    for (int i = 0; i < 4; ++i) {
        const int u = wave * 4 + i;            // unit index 0..15
        gA[i] = Wt + (size_t)(j0 + u * 8 + rl) * D_DIM + k0 + sl;
        gB[i] = Kb + (size_t)(c0 + u * 8 + rl) * D_DIM + k0 + sl;
    }

    auto stage = [&](int bsel, int t) {
        bf16_t* buf = stg + bsel * 16384;
#pragma unroll
        for (int i = 0; i < 4; ++i) {
            const int u = wave * 4 + i;
            gld16(gA[i] + t * 64, buf + (size_t)u * 512 + lane * 8);
            gld16(gB[i] + t * 64, buf + 8192 + (size_t)u * 512 + lane * 8);
        }
    };

#define K1_COMPUTE(BSEL)                                                     \
    {                                                                        \
        const bf16_t* buf = stg + (BSEL) * 16384;                            \
        const int r3 = l15 & 7, uh = l15 >> 3;                               \
        _Pragma("unroll")                                                    \
        for (int kk = 0; kk < 2; ++kk) {                                     \
            const int slot = r3 * 8 + ((kk * 4 + quad) ^ r3);                \
            bf16x8 af[4], bq[4];                                             \
            _Pragma("unroll")                                                \
            for (int mi = 0; mi < 4; ++mi)                                   \
                af[mi] = *(const bf16x8*)(                                   \
                    buf + (wm * 8 + mi * 2 + uh) * 512 + slot * 8);          \
            _Pragma("unroll")                                                \
            for (int ni = 0; ni < 4; ++ni)                                   \
                bq[ni] = *(const bf16x8*)(                                   \
                    buf + 8192 + (wn * 8 + ni * 2 + uh) * 512 + slot * 8);   \
            _Pragma("unroll")                                                \
            for (int mi = 0; mi < 4; ++mi)                                   \
                _Pragma("unroll")                                            \
                for (int ni = 0; ni < 4; ++ni)                               \
                    acc[mi][ni] = __builtin_amdgcn_mfma_f32_16x16x32_bf16(   \
                        af[mi], bq[ni], acc[mi][ni], 0, 0, 0);               \
        }                                                                    \
    }

    // 16 K-tiles of 64. Prologue: tile 0 -> buf0.
    stage(0, 0);
    __syncthreads();
#pragma unroll 1
    for (int t = 0; t < 14; t += 2) {
        stage(1, t + 1);
        __builtin_amdgcn_sched_barrier(0);
        K1_COMPUTE(0);                  // tile t
        __syncthreads();
        stage(0, t + 2);
        __builtin_amdgcn_sched_barrier(0);
        K1_COMPUTE(1);                  // tile t+1
        __syncthreads();
    }
    stage(1, 15);
    __builtin_amdgcn_sched_barrier(0);
    K1_COMPUTE(0);                      // tile 14
    __syncthreads();
    K1_COMPUTE(1);                      // tile 15

    // Barrier-free direct f32 epilogue into the ks partial slice.
    // acc[mi][ni][r] -> row = j0+wm*64+mi*16+quad*4+r, col = c0+wn*64+ni*16+l15.
    {
        float* rp = Rp + (size_t)ks * D_DIM * CTX_N;
        const size_t base =
            (size_t)(j0 + wm * 64 + quad * 4) * CTX_N + c0 + wn * 64 + l15;
#pragma unroll
        for (int mi = 0; mi < 4; ++mi)
#pragma unroll
            for (int r = 0; r < 4; ++r) {
                const size_t rowb = base + (size_t)(mi * 16 + r) * CTX_N;
#pragma unroll
                for (int ni = 0; ni < 4; ++ni)
                    rp[rowb + ni * 16] = acc[mi][ni][r];
            }
    }
}

// ---- K1b: Rt = (sum_ks Rp[ks]) - Vt, bf16.  Pure streaming reduce. ----
__global__ __launch_bounds__(256) void k1_reduce(
    const float* __restrict__ Rp, const bf16_t* __restrict__ Vt,
    bf16_t* __restrict__ Rt)
{
    const size_t base = ((size_t)blockIdx.x * 256 + threadIdx.x) * 8;
    const size_t slice = (size_t)D_DIM * CTX_N;

    f32x4 s0 = {}, s1 = {};
#pragma unroll
    for (int ks = 0; ks < 4; ++ks) {
        const f32x4 a = *(const f32x4*)(Rp + ks * slice + base);
        const f32x4 b = *(const f32x4*)(Rp + ks * slice + base + 4);
        s0 += a; s1 += b;
    }
    const bf16x8 vv = *(const bf16x8*)(Vt + base);
    bf16x8 o;
#pragma unroll
    for (int j = 0; j < 4; ++j) {
        o[j]     = (bf16_t)(s0[j] - (float)vv[j]);
        o[4 + j] = (bf16_t)(s1[j] - (float)vv[4 + j]);
    }
    *(bf16x8*)(Rt + base) = o;
}

// ---- K2: out[i][j] = W[i][j] - c * sum_c Kt[i][c]*Rt[j][c]  (4096x4096) ----
// BM=256(i) x BN=128(j), BK=32, 512 threads, 8 waves as 4m x 2n, each 64x64
// out (acc[4][4]). Grid (32,16) = 512 blocks = 2/CU. LDS 2 x 24 KB dbuf.
// Slot-XOR staging; barrier-free W-prefetch epilogue; bijective XCD swizzle.

#define K2_COMPUTE(BSEL)                                                      \
    {                                                                         \
        const bf16_t* bufA = stg + (BSEL) * 12288;                            \
        const bf16_t* bufB = bufA + 8192;                                     \
        const int sgx = (quad ^ (l15 & 3)) * 8;                               \
        bf16x8 af[4], bq[4];                                                  \
        _Pragma("unroll")                                                     \
        for (int mi = 0; mi < 4; ++mi)                                        \
            af[mi] = *(const bf16x8*)(                                        \
                bufA + ((wave >> 1) * 4 + mi) * 512 + l15 * 32 + sgx);        \
        _Pragma("unroll")                                                     \
        for (int ni = 0; ni < 4; ++ni)                                        \
            bq[ni] = *(const bf16x8*)(                                        \
                bufB + ((wave & 1) * 4 + ni) * 512 + l15 * 32 + sgx);         \
        _Pragma("unroll")                                                     \
        for (int mi = 0; mi < 4; ++mi)                                        \
            _Pragma("unroll")                                                 \
            for (int ni = 0; ni < 4; ++ni)                                    \
                acc[mi][ni] = __builtin_amdgcn_mfma_f32_16x16x32_bf16(        \
                    af[mi], bq[ni], acc[mi][ni], 0, 0, 0);                    \
    }

__global__ __launch_bounds__(512, 2) void k2_update(
    const bf16_t* __restrict__ Kt, const bf16_t* __restrict__ Rt,
    const float* __restrict__ W, float* __restrict__ out)
{
    __shared__ __align__(16) bf16_t stg[2 * 12288];  // 2 x 24 KB

    const int tid = threadIdx.x;

    // Bijective XCD swizzle over 512 blocks: id = (yp&7) + 8*xp + 256*(yp>>3).
    const int id = blockIdx.x + 32 * blockIdx.y;
    const int xp = (id >> 3) & 31;
    const int yp = (id & 7) + 8 * (id >> 8);
    const int j0 = xp * 128, i0 = yp * 256;

    const int lane = tid & 63, wave = tid >> 6;
    const int wi = (wave >> 1) * 64, wj = (wave & 1) * 64;
    const int l15 = lane & 15, quad = lane >> 4;

    f32x4 acc[4][4] = {};

    // Staging source (slot-XOR pre-permuted): lane l -> row l>>2, seg
    // (l&3)^((l>>2)&3) within its unit's 64B row window.
    const int rl = lane >> 2;                          // row in unit 0..15
    const int sl = ((lane & 3) ^ (rl & 3)) * 8;        // permuted seg (elems)
    const bf16_t* gA0 = Kt + (size_t)(i0 + wave * 16       + rl) * CTX_N + sl;
    const bf16_t* gA1 = Kt + (size_t)(i0 + wave * 16 + 128 + rl) * CTX_N + sl;
    const bf16_t* gB0 = Rt + (size_t)(j0 + wave * 16       + rl) * CTX_N + sl;

    auto stage = [&](int bsel, int cc) {
        bf16_t* buf = stg + bsel * 12288;
        gld16(gA0 + cc, buf + (size_t)wave * 512 + lane * 8);
        gld16(gA1 + cc, buf + (size_t)(wave + 8) * 512 + lane * 8);
        gld16(gB0 + cc, buf + 8192 + (size_t)wave * 512 + lane * 8);
    };

    // 16 K-tiles of 32. Prologue: tile 0 -> buf0.
    stage(0, 0);
    __syncthreads();
#pragma unroll 1
    for (int t = 1; t <= 13; t += 2) {
        stage(1, t * 32);
        __builtin_amdgcn_sched_barrier(0);
        K2_COMPUTE(0);                  // tile t-1
        __syncthreads();
        stage(0, (t + 1) * 32);
        __builtin_amdgcn_sched_barrier(0);
        K2_COMPUTE(1);                  // tile t
        __syncthreads();
    }
    stage(1, 15 * 32);
    __builtin_amdgcn_sched_barrier(0);
    K2_COMPUTE(0);                      // tile 14
    __syncthreads();
    K2_COMPUTE(1);                      // tile 15

    // ---- Barrier-free direct epilogue ----
    // acc[mi][ni][r] maps to row = i0+wi+mi*16+quad*4+r, col = j0+wj+ni*16+l15.
    const size_t base = (size_t)(i0 + wi + quad * 4) * D_DIM + j0 + wj + l15;
    const float* wp = W + base;
    float*       op = out + base;

    // Prefetch mi=0's 16 W fragments.
    float w0[16], w1[16];
#pragma unroll
    for (int r = 0; r < 4; ++r)
#pragma unroll
        for (int ni = 0; ni < 4; ++ni)
            w0[r * 4 + ni] = wp[(size_t)r * D_DIM + ni * 16];

#pragma unroll
    for (int mi = 0; mi < 4; ++mi) {
        float* wcur = (mi & 1) ? w1 : w0;
        float* wnxt = (mi & 1) ? w0 : w1;
        if (mi < 3) {
#pragma unroll
            for (int r = 0; r < 4; ++r)
#pragma unroll
                for (int ni = 0; ni < 4; ++ni)
                    wnxt[r * 4 + ni] =
                        wp[(size_t)((mi + 1) * 16 + r) * D_DIM + ni * 16];
        }
#pragma unroll
        for (int r = 0; r < 4; ++r)
#pragma unroll
            for (int ni = 0; ni < 4; ++ni)
                op[(size_t)(mi * 16 + r) * D_DIM + ni * 16] =
                    wcur[r * 4 + ni] - UPD_SCALE * acc[mi][ni][r];
    }
}

extern "C" void kernel_launch(void* const* d_in, const int* in_sizes, int n_in,
                              void* d_out, int out_size, void* d_ws, size_t ws_size,
                              hipStream_t stream) {
    const float* W = (const float*)d_in[0];   // (4096, 4096)
    const float* K = (const float*)d_in[1];   // (512, 4096)
    const float* V = (const float*)d_in[2];   // (512, 4096)
    float* out = (float*)d_out;

    char* ws = (char*)d_ws;                    // 80 MB used
    bf16_t* Wt = (bf16_t*)(ws);                            // (4096,4096) W^T
    bf16_t* Kt = (bf16_t*)(ws + (size_t)32 * 1024 * 1024); // (4096,512) K^T
    bf16_t* Kb = (bf16_t*)(ws + (size_t)36 * 1024 * 1024); // (512,4096) K
    bf16_t* Vt = (bf16_t*)(ws + (size_t)40 * 1024 * 1024); // (4096,512) V^T
    bf16_t* Rt = (bf16_t*)(ws + (size_t)44 * 1024 * 1024); // (4096,512) R^T
    float*  Rp = (float*) (ws + (size_t)48 * 1024 * 1024); // 4x(4096,512) f32

    t_all      <<<dim3(64, 80), 256, 0, stream>>>(W, K, V, Wt, Kt, Kb, Vt);
    k1_partial <<<dim3(32, 16), 256, 0, stream>>>(Wt, Kb, Rp);
    k1_reduce  <<<dim3(1024),   256, 0, stream>>>(Rp, Vt, Rt);
    k2_update  <<<dim3(32, 16), 512, 0, stream>>>(Kt, Rt, W, out);
}